// Round 1
// baseline (595.453 us; speedup 1.0000x reference)
//
#include <hip/hip_runtime.h>

// PiecewiseContEmbeddings: B=4096, N=64, K=128, E=512, fp32.
//
// Key identity: boundaries rows are sorted, so the reference's mask is
//   mask[b,n,k] = 1 (k < bidx), frac (k == bidx), 0 (k > bidx).
// Hence out[b,n,:] = relu( lerp(C[n,bidx,:], C[n,bidx+1,:], frac) )
// with C[n,j,:] = bias[n,:] + prefix_sum_k<j weight[n,k,:].
// Turns the O(B*N*K*E) einsum into an O(B*N*E) 2-row gather + lerp.

#define BB 4096
#define NN 64
#define KK 128
#define EE 512
#define EPSF 1e-8f

// ---- Kernel 1: C[n,j,e] = bias[n,e] + sum_{k<j} weight[n,k,e], j in [0,K]
// grid = N * (E/256) = 128 blocks, 256 threads; one thread per (n,e) column.
__global__ void cumsum_kernel(const float* __restrict__ weight,
                              const float* __restrict__ bias,
                              float* __restrict__ C) {
    int n = blockIdx.x >> 1;
    int e = ((blockIdx.x & 1) << 8) + threadIdx.x;   // 0..511
    const float* w = weight + ((size_t)n * KK) * EE + e;
    float*       c = C + ((size_t)n * (KK + 1)) * EE + e;
    float run = bias[n * EE + e];
    c[0] = run;
#pragma unroll 8
    for (int k = 0; k < KK; ++k) {
        run += w[(size_t)k * EE];
        c[(size_t)(k + 1) * EE] = run;
    }
}

// ---- Kernel 2: per (b,n) binary search -> bidx, frac
// thread i = b*N + n (coalesced X read)
__global__ void idx_kernel(const float* __restrict__ X,
                           const float* __restrict__ boundaries,
                           int* __restrict__ bidx_out,
                           float* __restrict__ frac_out) {
    int i = blockIdx.x * blockDim.x + threadIdx.x;   // b*N + n
    int n = i & (NN - 1);
    float x = X[i];
    const float* bnd = boundaries + n * (KK + 1);
    // lower_bound over inner = bnd[1 .. K-1]  (127 elements), result in [0,127]
    int lo = 0, hi = KK - 1;
    while (lo < hi) {
        int mid = (lo + hi) >> 1;
        if (bnd[1 + mid] < x) lo = mid + 1; else hi = mid;
    }
    float start = bnd[lo];
    float end   = bnd[lo + 1];
    bidx_out[i] = lo;
    frac_out[i] = (x - start) / (end - start + EPSF);
}

// ---- Kernel 3: out[b,n,:] = relu(lerp(C[n,bi,:], C[n,bi+1,:], frac))
// Work items ordered n-major (item t: n = t/B, b = t%B) so consecutive blocks
// share the same n -> C rows stay hot in L2. 4 items per block, 256 thr,
// float2 per thread (512 floats = one E-row).
__global__ void gather_kernel(const float* __restrict__ C,
                              const int* __restrict__ bidx,
                              const float* __restrict__ frac,
                              float* __restrict__ out) {
    int base = blockIdx.x << 2;
    int e = threadIdx.x << 1;
#pragma unroll
    for (int it = 0; it < 4; ++it) {
        int t = base + it;
        int n = t >> 12;          // t / B  (B = 4096)
        int b = t & (BB - 1);     // t % B
        int i = b * NN + n;
        int bi = __ldg(&bidx[i]);
        float f = __ldg(&frac[i]);
        const float2* c0 =
            (const float2*)(C + (((size_t)n * (KK + 1) + bi) * EE) + e);
        float2 lo = c0[0];
        float2 hi = c0[EE / 2];   // +E floats = next j row
        float2 r;
        r.x = fmaf(f, hi.x - lo.x, lo.x);
        r.y = fmaf(f, hi.y - lo.y, lo.y);
        r.x = fmaxf(r.x, 0.f);
        r.y = fmaxf(r.y, 0.f);
        *(float2*)(out + ((size_t)b * NN + n) * EE + e) = r;
    }
}

extern "C" void kernel_launch(void* const* d_in, const int* in_sizes, int n_in,
                              void* d_out, int out_size, void* d_ws, size_t ws_size,
                              hipStream_t stream) {
    const float* X          = (const float*)d_in[0];
    const float* boundaries = (const float*)d_in[1];
    const float* weight     = (const float*)d_in[2];
    const float* bias       = (const float*)d_in[3];
    float* out = (float*)d_out;

    // ws layout: C table | bidx | frac   (~18.2 MB total)
    float* C = (float*)d_ws;
    size_t Csz = (size_t)NN * (KK + 1) * EE;
    int*   bidx = (int*)(C + Csz);
    float* frac = (float*)(bidx + (size_t)BB * NN);

    cumsum_kernel<<<NN * (EE / 256), 256, 0, stream>>>(weight, bias, C);
    idx_kernel<<<(BB * NN) / 256, 256, 0, stream>>>(X, boundaries, bidx, frac);
    gather_kernel<<<(BB * NN) / 4, 256, 0, stream>>>(C, bidx, frac, out);
}